// Round 8
// baseline (71.263 us; speedup 1.0000x reference)
//
#include <hip/hip_runtime.h>

// Sinkhorn (eps=0.2, 50 iters), 64x64 images, b=64. Separable banded Gibbs:
// K = G (x) G, G[i,k]=exp(-5(i-k)^2), radius 2 in fp32.
//
// R8: all-b64 LDS traffic (the kernel is LDS-pipe ISSUE-bound: R6/R7 ran
// ~384 b32 DS wave-ops/CU/iter ~ 2230 cyc, matching the measured 2950
// cyc/iter; fewer instructions, same bytes, is the lever).
//   layout-A (V): lane (cl=l&31, hl=l>>5) owns rows r0..r0+3 (r0=8w+4hl),
//     col pair 2cl,2cl+1 (+/-2 halo rows kept in regs, recomputed each iter).
//   layout-B (U): lane (q=l&7, hq=l>>3) owns row rB=8w+q, cols 8hq..8hq+7
//     (um kept 12 wide so the horizontal conv needs no shuffles).
//   p1b transpose via wave-private S0: 4x ds_write_b64 + 8x ds_read_b64
//     (same-wave DS is in-order -> compiler barrier only).
//   p2b transpose via parity buffers S1a/S1b: 4x ds_write_b64 +
//     12x ds_read_b64, ONE __syncthreads per iteration (parity removes the
//     WAR barrier; syncthreads' lgkmcnt drain makes parity reuse safe).
// 28 b64 DS ops/wave/iter vs R7's 48 b32. Pitch 66: all float2 accesses
// 8B-aligned; bank starts uniform (4 lanes per even bank, 4 words/bank).
// R7 BUG FIXED: hq edge conditions are hq==0 / hq==7 (hq in [0,8)); R7's
// "hq==15" never fired, leaving cols 64..67 unzeroed (absmax 256).

#define PT 66
#define CBAR() asm volatile("" ::: "memory")

__device__ __forceinline__ float frcp_nr(float d) {
    float r = __builtin_amdgcn_rcpf(d);
    return r * fmaf(-d, r, 2.0f);   // 1 Newton step: ~1 ulp
}

// One Sinkhorn iteration; SW/SR = S1 parity write/read pointers.
#define ITER(SW, SR)                                                           \
  {                                                                            \
    float W[8][2], s4[4][2];                                                   \
    _Pragma("unroll") for (int c = 0; c < 2; ++c) {                            \
      W[0][c] = lo ? vh[0][c] : 0.f;  W[1][c] = lo ? vh[1][c] : 0.f;           \
      W[2][c] = vv[0][c]; W[3][c] = vv[1][c];                                  \
      W[4][c] = vv[2][c]; W[5][c] = vv[3][c];                                  \
      W[6][c] = hi ? vh[2][c] : 0.f;  W[7][c] = hi ? vh[3][c] : 0.f;           \
    }                                                                          \
    _Pragma("unroll") for (int k = 0; k < 4; ++k)                              \
      _Pragma("unroll") for (int c = 0; c < 2; ++c)                            \
        s4[k][c] = fmaf(g2, W[k][c] + W[k+4][c],                               \
                   fmaf(g1, W[k+1][c] + W[k+3][c], W[k+2][c]));                \
    _Pragma("unroll") for (int k = 0; k < 4; ++k)                              \
      *(float2*)(pS0w + PT * k) = make_float2(s4[k][0], s4[k][1]);             \
    CBAR();                                                                    \
    float R[16];                                                               \
    _Pragma("unroll") for (int j = 0; j < 8; ++j) {                            \
      float2 f = *(const float2*)(pS0rA + 2 * j);                              \
      R[2*j] = f.x; R[2*j+1] = f.y;                                            \
    }                                                                          \
    if (!clo) { R[0] = R[1] = R[2] = R[3] = 0.f; }                             \
    if (!chi) { R[12] = R[13] = R[14] = R[15] = 0.f; }                         \
    _Pragma("unroll") for (int j = 0; j < 12; ++j) {                           \
      float o = fmaf(g2, R[j] + R[j+4], fmaf(g1, R[j+1] + R[j+3], R[j+2]));    \
      um[j] = xv[j] * frcp_nr(o + 1e-8f);                                      \
    }                                                                          \
    float W2[12];                                                              \
    W2[0] = clo ? um[0] : 0.f;  W2[1] = clo ? um[1] : 0.f;                     \
    _Pragma("unroll") for (int j = 2; j < 10; ++j) W2[j] = um[j];              \
    W2[10] = chi ? um[10] : 0.f; W2[11] = chi ? um[11] : 0.f;                  \
    float s8[8];                                                               \
    _Pragma("unroll") for (int c = 0; c < 8; ++c)                              \
      s8[c] = fmaf(g2, W2[c] + W2[c+4], fmaf(g1, W2[c+1] + W2[c+3], W2[c+2])); \
    _Pragma("unroll") for (int c = 0; c < 4; ++c)                              \
      *(float2*)((SW) + 2 * c) = make_float2(s8[2*c], s8[2*c+1]);              \
    __syncthreads();                                                           \
    float Rv[12][2];                                                           \
    _Pragma("unroll") for (int m = 0; m < 12; ++m) {                           \
      float2 f = *(const float2*)((SR) + PT * m);                              \
      Rv[m][0] = f.x; Rv[m][1] = f.y;                                          \
    }                                                                          \
    if (!lo) { _Pragma("unroll") for (int m = 0; m < 4; ++m)                   \
                 { Rv[m][0] = 0.f; Rv[m][1] = 0.f; } }                         \
    if (!hi) { _Pragma("unroll") for (int m = 8; m < 12; ++m)                  \
                 { Rv[m][0] = 0.f; Rv[m][1] = 0.f; } }                         \
    float e[8][2];                                                             \
    _Pragma("unroll") for (int m = 0; m < 8; ++m)                              \
      _Pragma("unroll") for (int c = 0; c < 2; ++c)                            \
        e[m][c] = fmaf(g2, Rv[m][c] + Rv[m+4][c],                              \
                  fmaf(g1, Rv[m+1][c] + Rv[m+3][c], Rv[m+2][c]));              \
    _Pragma("unroll") for (int k = 0; k < 4; ++k)                              \
      _Pragma("unroll") for (int c = 0; c < 2; ++c)                            \
        vv[k][c] = yv[k+2][c] * frcp_nr(e[k+2][c] + 1e-8f);                    \
    _Pragma("unroll") for (int c = 0; c < 2; ++c) {                            \
      vh[0][c] = yv[0][c] * frcp_nr(e[0][c] + 1e-8f);                          \
      vh[1][c] = yv[1][c] * frcp_nr(e[1][c] + 1e-8f);                          \
      vh[2][c] = yv[6][c] * frcp_nr(e[6][c] + 1e-8f);                          \
      vh[3][c] = yv[7][c] * frcp_nr(e[7][c] + 1e-8f);                          \
    }                                                                          \
  }

extern "C" __global__ void __launch_bounds__(512)
sinkhorn_kernel(const float* __restrict__ x, const float* __restrict__ y,
                const float* __restrict__ cost, const float* __restrict__ kern,
                float* __restrict__ partials)
{
    // [pad 272][S1a 4224][pad 272][S1b 4224][pad 272][S0 4224][pad][wsum 8]
    __shared__ __align__(16) float lds[13768];
    float* const S1a  = lds + 272;
    float* const S1b  = lds + 4768;
    float* const S0   = lds + 9264;
    float* const wsum = lds + 13760;

    const int t  = threadIdx.x;
    const int l  = t & 63;
    const int w  = t >> 6;          // wave 0..7 owns rows [8w, 8w+8)
    const int q  = l & 7;
    const int hq = l >> 3;          // 0..7
    const int rB = 8 * w + q;       // layout-B row
    const int c0 = 8 * hq;          // layout-B col base
    const int cl = l & 31;          // layout-A col pair (2cl, 2cl+1)
    const int hl = l >> 5;          // 0..1
    const int r0 = 8 * w + 4 * hl;  // layout-A row base (4 rows)
    const int b  = blockIdx.x;

    const float g1 = kern[(size_t)64  * 4096];        // e^-5
    const float g2 = kern[(size_t)128 * 4096];        // e^-20
    const float q1 = cost[(size_t)64  * 4096] * g1;   // 1*e^-5
    const float q2 = cost[(size_t)128 * 4096] * g2;   // 4*e^-20

    // loop-invariant LDS pointers (b64 with immediate offsets)
    float* const pS0w = S0 + PT * r0 + 2 * cl;          // p1b writes [+PT*k]
    const float* const pS0rA = S0 + PT * rB + c0 - 4;   // p1b reads  [+2j], 8x
    const float* const pS0rB = S0 + PT * rB + c0 - 2;   // epilogue   [+2j], 6x
    float* const pSaw = S1a + PT * rB + c0;             // p2b writes [+2c]
    const float* const pSar = S1a + PT * (r0 - 4) + 2 * cl; // p2b reads [+PT*m]
    float* const pSbw = S1b + PT * rB + c0;
    const float* const pSbr = S1b + PT * (r0 - 4) + 2 * cl;

    const bool lo  = (r0 != 0), hi = (r0 != 60);      // vertical edges
    const bool clo = (hq != 0), chi = (hq != 7);      // horizontal edges

    // marginals in registers for all 50 iters
    float xv[12], yv[8][2];
    {
        const float* xr = x + (size_t)b * 4096 + 64 * rB;
#pragma unroll
        for (int j = 0; j < 12; ++j) {
            int cc = c0 - 2 + j;                       // col of um[j]
            cc = cc < 0 ? 0 : (cc > 63 ? 63 : cc);     // clamp (OOB unused)
            xv[j] = xr[cc];
        }
        const float* yb = y + (size_t)b * 4096 + 2 * cl;
#pragma unroll
        for (int m = 0; m < 8; ++m) {
            int rr = r0 - 2 + m;                       // rows r0-2 .. r0+5
            rr = rr < 0 ? 0 : (rr > 63 ? 63 : rr);
            float2 f = *(const float2*)(yb + 64 * rr);
            yv[m][0] = f.x; yv[m][1] = f.y;
        }
    }

    // state: V 4x2 tile + 4x2 halo rows (layout-A), U 12-wide (layout-B)
    float vv[4][2], vh[4][2], um[12];
#pragma unroll
    for (int k = 0; k < 4; ++k) {
        vv[k][0] = vv[k][1] = 1.0f / 4096.0f;
        vh[k][0] = vh[k][1] = 1.0f / 4096.0f;
    }

#pragma unroll 1
    for (int it2 = 0; it2 < 25; ++it2) {
        ITER(pSaw, pSar)
        ITER(pSbw, pSbr)
    }

    // ---- distance: sum U o ((G2*V)*G) + sum U o ((G*V)*G2)
    // S0 wave-private; same-wave DS in-order => compiler barriers only.
    float acc = 0.0f;
    {
        float W[8][2], s4[4][2], R[12], o;
#pragma unroll
        for (int c = 0; c < 2; ++c) {
            W[0][c] = lo ? vh[0][c] : 0.f;  W[1][c] = lo ? vh[1][c] : 0.f;
            W[2][c] = vv[0][c]; W[3][c] = vv[1][c];
            W[4][c] = vv[2][c]; W[5][c] = vv[3][c];
            W[6][c] = hi ? vh[2][c] : 0.f;  W[7][c] = hi ? vh[3][c] : 0.f;
        }
        // round 1: vertical q-taps, horizontal g-taps
#pragma unroll
        for (int k = 0; k < 4; ++k)
#pragma unroll
            for (int c = 0; c < 2; ++c)
                s4[k][c] = fmaf(q2, W[k][c] + W[k+4][c],
                                q1 * (W[k+1][c] + W[k+3][c]));
#pragma unroll
        for (int k = 0; k < 4; ++k)
            *(float2*)(pS0w + PT * k) = make_float2(s4[k][0], s4[k][1]);
        CBAR();
#pragma unroll
        for (int j = 0; j < 6; ++j) {
            float2 f = *(const float2*)(pS0rB + 2 * j);
            R[2*j] = f.x; R[2*j+1] = f.y;
        }
        if (!clo) { R[0] = R[1] = 0.f; }
        if (!chi) { R[10] = R[11] = 0.f; }
#pragma unroll
        for (int c = 0; c < 8; ++c) {
            o = fmaf(g2, R[c] + R[c+4], fmaf(g1, R[c+1] + R[c+3], R[c+2]));
            acc = fmaf(um[c + 2], o, acc);
        }
        CBAR();   // order round-1 reads before round-2 writes (same wave)
        // round 2: vertical g-taps, horizontal q-taps
#pragma unroll
        for (int k = 0; k < 4; ++k)
#pragma unroll
            for (int c = 0; c < 2; ++c)
                s4[k][c] = fmaf(g2, W[k][c] + W[k+4][c],
                           fmaf(g1, W[k+1][c] + W[k+3][c], W[k+2][c]));
#pragma unroll
        for (int k = 0; k < 4; ++k)
            *(float2*)(pS0w + PT * k) = make_float2(s4[k][0], s4[k][1]);
        CBAR();
#pragma unroll
        for (int j = 0; j < 6; ++j) {
            float2 f = *(const float2*)(pS0rB + 2 * j);
            R[2*j] = f.x; R[2*j+1] = f.y;
        }
        if (!clo) { R[0] = R[1] = 0.f; }
        if (!chi) { R[10] = R[11] = 0.f; }
#pragma unroll
        for (int c = 0; c < 8; ++c) {
            o = fmaf(q2, R[c] + R[c+4], q1 * (R[c+1] + R[c+3]));
            acc = fmaf(um[c + 2], o, acc);
        }
    }

    // deterministic reduction: wave shfl tree, then fixed-order 8-way sum
#pragma unroll
    for (int off = 32; off > 0; off >>= 1)
        acc += __shfl_down(acc, off, 64);
    if (l == 0) wsum[w] = acc;
    __syncthreads();
    if (t == 0) {
        partials[b] = ((wsum[0] + wsum[1]) + (wsum[2] + wsum[3]))
                    + ((wsum[4] + wsum[5]) + (wsum[6] + wsum[7]));
    }
}

extern "C" __global__ void __launch_bounds__(64)
reduce_kernel(const float* __restrict__ partials, float* __restrict__ out)
{
    int t = threadIdx.x;
    float v = partials[t];
#pragma unroll
    for (int off = 32; off > 0; off >>= 1)
        v += __shfl_down(v, off, 64);
    if (t == 0) out[0] = v;
}

extern "C" void kernel_launch(void* const* d_in, const int* in_sizes, int n_in,
                              void* d_out, int out_size, void* d_ws, size_t ws_size,
                              hipStream_t stream)
{
    const float* x    = (const float*)d_in[0];
    const float* y    = (const float*)d_in[1];
    const float* cost = (const float*)d_in[2];
    const float* kern = (const float*)d_in[3];
    float* partials   = (float*)d_ws;   // 64 floats

    sinkhorn_kernel<<<64, 512, 0, stream>>>(x, y, cost, kern, partials);
    reduce_kernel<<<1, 64, 0, stream>>>(partials, (float*)d_out);
}

// Round 9
// 62.076 us; speedup vs baseline: 1.1480x; 1.1480x over previous
//
#include <hip/hip_runtime.h>

// Sinkhorn (eps=0.2, 50 iters), 64x64 images, b=64. Separable banded Gibbs:
// K = G (x) G, G[i,k]=exp(-5(i-k)^2), radius 2 in fp32.
//
// R9: LDS-free data path. Lane = image row (64 lanes = 64 rows); wave w of 4
// owns cols 16w..16w+15 as 16 VGPRs. Horizontal conv: in-register (cols are
// regs). Vertical conv: DPP wave_shr:1 (0x138, out[r]=in[r-1]) and wave_shl:1
// (0x130, out[r]=in[r+1]) with bound_ctrl 0-fill = exact zero-padded edges;
// +-2 taps via chained shifts. DPP rides the VALU pipe -- the LDS transposes
// that bounded R4-R8 (~75 KB/iter/CU through a ~44 B/cyc pipe) are GONE.
// Remaining LDS: per K-apply each wave exchanges its 2+2 edge columns
// (4 ds_write_b32 + 4 ds_read_b32, lane-consecutive = conflict-free) with one
// __syncthreads; two alternating buffers make cross-iteration WAR safe
// (reads of buffer p complete before the NEXT apply's barrier, which orders
// them against the p-writes one apply later).
// Per-element arithmetic (taps, fma forms, NR rcp) is bitwise identical to R6.

template<int CTRL>
__device__ __forceinline__ float dppf(float v) {
    return __builtin_bit_cast(float,
        __builtin_amdgcn_update_dpp(0, __builtin_bit_cast(int, v),
                                    CTRL, 0xF, 0xF, true));
}
#define SHR1(v) dppf<0x138>(v)   // out[r] = in[r-1], row 0 gets 0
#define SHL1(v) dppf<0x130>(v)   // out[r] = in[r+1], row 63 gets 0

__device__ __forceinline__ float frcp_nr(float d) {
    float r = __builtin_amdgcn_rcpf(d);
    return r * fmaf(-d, r, 2.0f);   // 1 Newton step: ~1 ulp
}

// One K-apply: vertical 5-tap conv (DPP) -> edge-col exchange via LDS ->
// horizontal 5-tap conv (registers). VC/HC: include center tap (G) or not (G2).
template<bool VC, bool HC>
__device__ __forceinline__ void kapply(const float* __restrict__ s,
                                       float* __restrict__ o,
                                       float* __restrict__ ebw,
                                       const float* __restrict__ ebl,
                                       const float* __restrict__ ebr,
                                       float vt1, float vt2,
                                       float ht1, float ht2)
{
    float tv[16];
#pragma unroll
    for (int c = 0; c < 16; ++c) {
        float m1 = SHR1(s[c]), p1 = SHL1(s[c]);
        float m2 = SHR1(m1),   p2 = SHL1(p1);
        float s1 = m1 + p1,    s2 = m2 + p2;
        tv[c] = VC ? fmaf(vt2, s2, fmaf(vt1, s1, s[c]))
                   : fmaf(vt2, s2, vt1 * s1);
    }
    // publish edge cols: slots e=0,1,2,3 <-> cols +0,+1,+14,+15
    ebw[0]   = tv[0];
    ebw[64]  = tv[1];
    ebw[128] = tv[14];
    ebw[192] = tv[15];
    __syncthreads();
    float hl2 = ebl[128], hl1 = ebl[192];   // left neighbor cols 16w-2, 16w-1
    float hr1 = ebr[0],   hr2 = ebr[64];    // right neighbor cols 16w+16, +17
    float W[20];
    W[0] = hl2; W[1] = hl1;
#pragma unroll
    for (int c = 0; c < 16; ++c) W[c + 2] = tv[c];
    W[18] = hr1; W[19] = hr2;
#pragma unroll
    for (int c = 0; c < 16; ++c) {
        float s1 = W[c + 1] + W[c + 3], s2 = W[c] + W[c + 4];
        o[c] = HC ? fmaf(ht2, s2, fmaf(ht1, s1, W[c + 2]))
                  : fmaf(ht2, s2, ht1 * s1);
    }
}

extern "C" __global__ void __launch_bounds__(256)
sinkhorn_kernel(const float* __restrict__ x, const float* __restrict__ y,
                const float* __restrict__ cost, const float* __restrict__ kern,
                float* __restrict__ partials)
{
    // two halo buffers: [6 w-slots][4 e-slots][64 lanes]; w-slots -1 and 4 are
    // permanent zero guards (image edge zero-padding)
    __shared__ float EB[2][1536];
    __shared__ float wsum[4];

    const int t = threadIdx.x;
    const int r = t & 63;        // lane = row
    const int w = t >> 6;        // wave = col group (cols 16w..16w+15)
    const int b = blockIdx.x;

    // zero both buffers once (guards stay zero forever)
    for (int i = t; i < 3072; i += 256) ((float*)EB)[i] = 0.0f;

    const float g1 = kern[(size_t)64  * 4096];        // e^-5
    const float g2 = kern[(size_t)128 * 4096];        // e^-20
    const float q1 = cost[(size_t)64  * 4096] * g1;   // 1*e^-5
    const float q2 = cost[(size_t)128 * 4096] * g2;   // 4*e^-20

    float* const ebw0 = &EB[0][(w + 1) * 256 + r];
    const float* const ebl0 = &EB[0][w * 256 + r];
    const float* const ebr0 = &EB[0][(w + 2) * 256 + r];
    float* const ebw1 = &EB[1][(w + 1) * 256 + r];
    const float* const ebl1 = &EB[1][w * 256 + r];
    const float* const ebr1 = &EB[1][(w + 2) * 256 + r];

    // marginals: x[b][r][16w+c], y[b][r][16w+c] in registers (float4 loads)
    float xv[16], yv[16];
    {
        const float* xb = x + (size_t)b * 4096 + 64 * r + 16 * w;
        const float* yb = y + (size_t)b * 4096 + 64 * r + 16 * w;
#pragma unroll
        for (int j = 0; j < 4; ++j) {
            float4 f = *(const float4*)(xb + 4 * j);
            xv[4*j] = f.x; xv[4*j+1] = f.y; xv[4*j+2] = f.z; xv[4*j+3] = f.w;
            f = *(const float4*)(yb + 4 * j);
            yv[4*j] = f.x; yv[4*j+1] = f.y; yv[4*j+2] = f.z; yv[4*j+3] = f.w;
        }
    }

    float V[16], U[16], tb[16];
#pragma unroll
    for (int c = 0; c < 16; ++c) V[c] = 1.0f / 4096.0f;

#pragma unroll 1
    for (int it = 0; it < 50; ++it) {
        // U = x / (G*V*G + 1e-8)
        kapply<true, true>(V, tb, ebw0, ebl0, ebr0, g1, g2, g1, g2);
#pragma unroll
        for (int c = 0; c < 16; ++c) U[c] = xv[c] * frcp_nr(tb[c] + 1e-8f);
        // V = y / (G*U*G + 1e-8)
        kapply<true, true>(U, tb, ebw1, ebl1, ebr1, g1, g2, g1, g2);
#pragma unroll
        for (int c = 0; c < 16; ++c) V[c] = yv[c] * frcp_nr(tb[c] + 1e-8f);
    }

    // distance: sum U o ((G2*V)*G) + sum U o ((G*V)*G2)
    float acc = 0.0f;
    kapply<false, true>(V, tb, ebw0, ebl0, ebr0, q1, q2, g1, g2);
#pragma unroll
    for (int c = 0; c < 16; ++c) acc = fmaf(U[c], tb[c], acc);
    kapply<true, false>(V, tb, ebw1, ebl1, ebr1, g1, g2, q1, q2);
#pragma unroll
    for (int c = 0; c < 16; ++c) acc = fmaf(U[c], tb[c], acc);

    // deterministic reduction: wave shfl tree, then fixed-order 4-way sum
#pragma unroll
    for (int off = 32; off > 0; off >>= 1)
        acc += __shfl_down(acc, off, 64);
    if (r == 0) wsum[w] = acc;
    __syncthreads();
    if (t == 0)
        partials[b] = (wsum[0] + wsum[1]) + (wsum[2] + wsum[3]);
}

extern "C" __global__ void __launch_bounds__(64)
reduce_kernel(const float* __restrict__ partials, float* __restrict__ out)
{
    int t = threadIdx.x;
    float v = partials[t];
#pragma unroll
    for (int off = 32; off > 0; off >>= 1)
        v += __shfl_down(v, off, 64);
    if (t == 0) out[0] = v;
}

extern "C" void kernel_launch(void* const* d_in, const int* in_sizes, int n_in,
                              void* d_out, int out_size, void* d_ws, size_t ws_size,
                              hipStream_t stream)
{
    const float* x    = (const float*)d_in[0];
    const float* y    = (const float*)d_in[1];
    const float* cost = (const float*)d_in[2];
    const float* kern = (const float*)d_in[3];
    float* partials   = (float*)d_ws;   // 64 floats

    sinkhorn_kernel<<<64, 256, 0, stream>>>(x, y, cost, kern, partials);
    reduce_kernel<<<1, 64, 0, stream>>>(partials, (float*)d_out);
}